// Round 4
// baseline (261.730 us; speedup 1.0000x reference)
//
#include <hip/hip_runtime.h>

// ComplexSKPDELayer — MFMA formulation (R8: prep-kernel offload + c-outer).
// R7 counters taught: (1) VGPR_Count=128 is arch-only; the 40xf4 accumulator
// block adds >=160 AGPRs -> combined >256/wave -> 1-2 waves/SIMD regardless
// of grid (occupancy stuck at 16.5%). (2) per-block prep ~16us (dR7-R1=33us
// for 2 extra preps/CU; bank conflicts 1536/block = pack ds_writes).
// Fixes: (a) one-time prep kernel packs W2(fp16 B-frag order)+derived consts
// into d_ws; main blocks do a conflict-free 36KiB float4 copy. (b) c-outer
// loop: keep 20 A-frags (80 VGPR) live, only 5 f4 accums + 16 result regs;
// epilogue fused per-c. launch_bounds(256,3) caps combined at 170 -> 3
// waves/SIMD target. Watch WRITE_SIZE for spill (R6 lesson).
//
// Math (unchanged): per interior point, Helmholtz residual = 5 matvecs
// through W2: rows h1,g1x,g1y,g1z,s1 -> z2,ux,uy,uz,t; h2=tanh(z2+b2);
// lap_k=d2*(t-2*h2*(ux^2+uy^2+uz^2)); helm=(lap_k+4*h2)@W3(+4*b3).
// C/D layout col=lane&15(=k), row=(lane>>4)*4+reg(=point) -> lane-local
// epilogue + 16-lane shfl reduce. fp16 absmax ~0.008 vs 0.27 threshold.

#define N_INT 262144
#define N_BC  65536
#define HID   128
#define GRID  1024
#define WPB   4                      // waves per 256-thread block
#define NWAVE (GRID * WPB)           // 4096 waves
#define TILES_INT (N_INT / 16)       // 16384
#define TILES_BC  (N_BC / 16)        // 4096
#define TILES_ALL (TILES_INT + TILES_BC)   // 20480 = 4096 * 5, no tail

typedef _Float16 h8 __attribute__((ext_vector_type(8)));
typedef float    f4 __attribute__((ext_vector_type(4)));

__device__ __forceinline__ float ftanh(float x) {
    // tanh(x) = 1 - 2/(e^{2x}+1); v_exp_f32 + v_rcp_f32, ~2 ulp, inf-safe
    float e = __expf(2.0f * x);
    return 1.0f - 2.0f * __builtin_amdgcn_rcpf(e + 1.0f);
}

// ---------------- one-time prep: pack W2 + derived consts into ws ----------
// wsB (offset 0):      16384 fp16 = 32 KiB, B-frag order:
//   wsB[(((s*8+c)*64)+(qd*16+nn))*8+i] = fp16 W2[s*32+qd*8+i][c*16+nn]
// wsF (offset 32768):  1024 f32 = 4 KiB:
//   [0:128) Wx  [128:256) Wy  [256:384) Wz  [384:512) C1=b1+latent@W1[3:]
//   [512:640) Q2=-2*(Wx^2+Wy^2+Wz^2)  [640:768) b2  [768:1024) W3 (128x2)
extern "C" __global__ void pde_prep(const float* __restrict__ latent,
                                    const float* __restrict__ W1,
                                    const float* __restrict__ b1,
                                    const float* __restrict__ W2,
                                    const float* __restrict__ b2,
                                    const float* __restrict__ W3,
                                    _Float16* __restrict__ wsB,
                                    float* __restrict__ wsF)
{
    const int tid = threadIdx.x;
    for (int e = 0; e < 64; ++e) {
        int idx = e * 256 + tid;                   // coalesced over W2 row-major
        int j = idx >> 7, n = idx & 127;           // j = K row, n = out col
        int s = j >> 5, qd = (j >> 3) & 3, i = j & 7;
        int c = n >> 4,  nn = n & 15;
        wsB[(((s * 8 + c) * 64) + (qd * 16 + nn)) * 8 + i] = (_Float16)W2[idx];
    }
    // latent reduction: 2 threads per column, 32-deep chains, shfl combine
    {
        int col = tid >> 1, h = tid & 1;
        float acc = 0.0f;
        #pragma unroll
        for (int l = 0; l < 32; ++l)
            acc = fmaf(latent[32 * h + l], W1[(3 + 32 * h + l) * HID + col], acc);
        acc += __shfl_xor(acc, 1);
        if (h == 0) wsF[384 + col] = acc + b1[col];
    }
    if (tid < HID) {
        float wx = W1[tid], wy = W1[HID + tid], wz = W1[2 * HID + tid];
        wsF[tid] = wx; wsF[128 + tid] = wy; wsF[256 + tid] = wz;
        wsF[512 + tid] = -2.0f * fmaf(wx, wx, fmaf(wy, wy, wz * wz));
        wsF[640 + tid] = b2[tid];
        wsF[768 + 2 * tid]     = W3[2 * tid];
        wsF[768 + 2 * tid + 1] = W3[2 * tid + 1];
    }
}

extern "C" __global__ __launch_bounds__(256, 3)
void pde_mfma(const float* __restrict__ ci, const float* __restrict__ cb,
              const float* __restrict__ gt, const float* __restrict__ b3,
              const _Float16* __restrict__ wsB, const float* __restrict__ wsF,
              float* __restrict__ out)
{
    __shared__ float4 sBv[2048];       // 32 KiB packed W2 B-frags
    __shared__ float4 sFv[256];        // 4 KiB derived consts
    _Float16* sB = (_Float16*)sBv;
    const float* sF  = (const float*)sFv;
    const float* sWx = sF;
    const float* sWy = sF + 128;
    const float* sWz = sF + 256;
    const float* sC1 = sF + 384;
    const float* sQ2 = sF + 512;
    const float* sB2 = sF + 640;
    const float2* sW3 = (const float2*)(sF + 768);

    const int tid = threadIdx.x;

    // conflict-free staging copy: 32 KiB + 4 KiB as float4
    #pragma unroll
    for (int e = 0; e < 8; ++e)
        sBv[e * 256 + tid] = ((const float4*)wsB)[e * 256 + tid];
    sFv[tid] = ((const float4*)wsF)[tid];
    __syncthreads();

    const int lane = tid & 63;
    const int m    = lane & 15;        // point-in-tile (C col index k's partner)
    const int qd   = lane >> 4;        // quad: k-subrange / C row block
    const int wgid = blockIdx.x * WPB + (tid >> 6);
    const float b30 = b3[0], b31 = b3[1];
    const f4 z4 = {0.0f, 0.0f, 0.0f, 0.0f};

    float lsum = 0.0f, bsum = 0.0f;

    for (int t = wgid; t < TILES_ALL; t += NWAVE) {
      if (t < TILES_INT) {
        // ================= interior tile: 16 points =================
        const int p0 = t * 16;
        const int pt = p0 + m;
        const float x = ci[3 * pt], y = ci[3 * pt + 1], z = ci[3 * pt + 2];

        // A-frags for all 4 k-slices (80 VGPRs live)
        h8 FH[4], FX[4], FY[4], FZ[4], FT[4];
        #pragma unroll
        for (int s = 0; s < 4; ++s) {
            const int j0 = s * 32 + qd * 8;
            #pragma unroll
            for (int i = 0; i < 8; ++i) {
                const int j = j0 + i;
                float wx = sWx[j], wy = sWy[j], wz = sWz[j];
                float z1 = fmaf(x, wx, fmaf(y, wy, fmaf(z, wz, sC1[j])));
                float h  = ftanh(z1);
                float d  = fmaf(-h, h, 1.0f);
                FH[s][i] = (_Float16)h;
                FX[s][i] = (_Float16)(d * wx);
                FY[s][i] = (_Float16)(d * wy);
                FZ[s][i] = (_Float16)(d * wz);
                FT[s][i] = (_Float16)(sQ2[j] * h * d);
            }
        }

        float yr[4] = {0,0,0,0}, yi[4] = {0,0,0,0};
        float lr[4] = {0,0,0,0}, li[4] = {0,0,0,0};
        #pragma unroll
        for (int c = 0; c < 8; ++c) {
            f4 aZ = z4, aX = z4, aY = z4, aW = z4, aT = z4;
            #pragma unroll
            for (int s = 0; s < 4; ++s) {
                h8 bf = *(const h8*)&sB[(((s * 8 + c) * 64) + lane) * 8];
                aZ = __builtin_amdgcn_mfma_f32_16x16x32_f16(FH[s], bf, aZ, 0, 0, 0);
                aX = __builtin_amdgcn_mfma_f32_16x16x32_f16(FX[s], bf, aX, 0, 0, 0);
                aY = __builtin_amdgcn_mfma_f32_16x16x32_f16(FY[s], bf, aY, 0, 0, 0);
                aW = __builtin_amdgcn_mfma_f32_16x16x32_f16(FZ[s], bf, aW, 0, 0, 0);
                aT = __builtin_amdgcn_mfma_f32_16x16x32_f16(FT[s], bf, aT, 0, 0, 0);
            }
            // fused epilogue for this c: lane-local (point=qd*4+r, k=c*16+m)
            const int k = c * 16 + m;
            const float b2k = sB2[k];
            const float2 w3 = sW3[k];
            #pragma unroll
            for (int r = 0; r < 4; ++r) {
                float h2 = ftanh(aZ[r] + b2k);
                float d2 = fmaf(-h2, h2, 1.0f);
                float uu = fmaf(aX[r], aX[r], fmaf(aY[r], aY[r], aW[r] * aW[r]));
                float lk = d2 * fmaf(-2.0f * h2, uu, aT[r]);
                yr[r] = fmaf(h2, w3.x, yr[r]);
                yi[r] = fmaf(h2, w3.y, yi[r]);
                lr[r] = fmaf(lk, w3.x, lr[r]);
                li[r] = fmaf(lk, w3.y, li[r]);
            }
        }
        #pragma unroll
        for (int off = 1; off <= 8; off <<= 1) {
            #pragma unroll
            for (int r = 0; r < 4; ++r) {
                yr[r] += __shfl_xor(yr[r], off);
                yi[r] += __shfl_xor(yi[r], off);
                lr[r] += __shfl_xor(lr[r], off);
                li[r] += __shfl_xor(li[r], off);
            }
        }
        if (m == 0) {
            #pragma unroll
            for (int r = 0; r < 4; ++r) {
                float re = fmaf(4.0f, yr[r] + b30, lr[r]);
                float im = fmaf(4.0f, yi[r] + b31, li[r]);
                out[2 + p0 + qd * 4 + r] = re;
                lsum = fmaf(re, re, fmaf(im, im, lsum));
            }
        }
      } else {
        // ================= boundary tile: 16 points, forward only =================
        const int q0 = (t - TILES_INT) * 16;
        const int pt = q0 + m;
        const float x = cb[3 * pt], y = cb[3 * pt + 1], z = cb[3 * pt + 2];

        h8 FH[4];
        #pragma unroll
        for (int s = 0; s < 4; ++s) {
            const int j0 = s * 32 + qd * 8;
            #pragma unroll
            for (int i = 0; i < 8; ++i) {
                const int j = j0 + i;
                float z1 = fmaf(x, sWx[j], fmaf(y, sWy[j], fmaf(z, sWz[j], sC1[j])));
                FH[s][i] = (_Float16)ftanh(z1);
            }
        }

        float yr[4] = {0,0,0,0}, yi[4] = {0,0,0,0};
        #pragma unroll
        for (int c = 0; c < 8; ++c) {
            f4 aZ = z4;
            #pragma unroll
            for (int s = 0; s < 4; ++s) {
                h8 bf = *(const h8*)&sB[(((s * 8 + c) * 64) + lane) * 8];
                aZ = __builtin_amdgcn_mfma_f32_16x16x32_f16(FH[s], bf, aZ, 0, 0, 0);
            }
            const int k = c * 16 + m;
            const float b2k = sB2[k];
            const float2 w3 = sW3[k];
            #pragma unroll
            for (int r = 0; r < 4; ++r) {
                float h2 = ftanh(aZ[r] + b2k);
                yr[r] = fmaf(h2, w3.x, yr[r]);
                yi[r] = fmaf(h2, w3.y, yi[r]);
            }
        }
        #pragma unroll
        for (int off = 1; off <= 8; off <<= 1) {
            #pragma unroll
            for (int r = 0; r < 4; ++r) {
                yr[r] += __shfl_xor(yr[r], off);
                yi[r] += __shfl_xor(yi[r], off);
            }
        }
        if (m == 0) {
            #pragma unroll
            for (int r = 0; r < 4; ++r) {
                float dr = yr[r] + b30 - gt[q0 + qd * 4 + r];
                float di = yi[r] + b31;
                bsum = fmaf(dr, dr, fmaf(di, di, bsum));
            }
        }
      }
    }

    // wave-wide loss reduction, one atomic per wave
    #pragma unroll
    for (int off = 1; off < 64; off <<= 1) {
        lsum += __shfl_xor(lsum, off);
        bsum += __shfl_xor(bsum, off);
    }
    if (lane == 0) {
        atomicAdd(out,     lsum * (1.0f / (float)N_INT));
        atomicAdd(out + 1, bsum * (1.0f / (float)N_BC));
    }
}

extern "C" void kernel_launch(void* const* d_in, const int* in_sizes, int n_in,
                              void* d_out, int out_size, void* d_ws, size_t ws_size,
                              hipStream_t stream)
{
    const float* ci  = (const float*)d_in[0];   // coords_int (262144,3)
    const float* cb  = (const float*)d_in[1];   // coords_bc  (65536,3)
    const float* gt  = (const float*)d_in[2];   // gt_bc      (65536,1)
    const float* lat = (const float*)d_in[3];   // latent     (64,)
    const float* W1  = (const float*)d_in[4];   // (67,128)
    const float* b1  = (const float*)d_in[5];   // (128,)
    const float* W2  = (const float*)d_in[6];   // (128,128)
    const float* b2  = (const float*)d_in[7];   // (128,)
    const float* W3  = (const float*)d_in[8];   // (128,2)
    const float* b3  = (const float*)d_in[9];   // (2,)
    float* out = (float*)d_out;   // [loss_pde, loss_bc, re(helm)*N_INT]

    _Float16* wsB = (_Float16*)d_ws;                       // 32 KiB packed W2
    float*    wsF = (float*)((char*)d_ws + 32768);         // 4 KiB consts

    // zero the two loss accumulators (out is poisoned 0xAA before every call)
    hipMemsetAsync(d_out, 0, 2 * sizeof(float), stream);

    hipLaunchKernelGGL(pde_prep, dim3(1), dim3(256), 0, stream,
                       lat, W1, b1, W2, b2, W3, wsB, wsF);
    hipLaunchKernelGGL(pde_mfma, dim3(GRID), dim3(256), 0, stream,
                       ci, cb, gt, b3, wsB, wsF, out);
}

// Round 5
// 195.883 us; speedup vs baseline: 1.3362x; 1.3362x over previous
//
#include <hip/hip_runtime.h>

// ComplexSKPDELayer — MFMA formulation (R9: c-outer, no-spill budget, latency cuts).
// Ledger: R1 118us (c-inner, (256,2), VGPR=128+AGPR, no spill, 16us/block prep).
// R6 636us: launch_bounds(512,4) -> 64-reg budget -> 1.5GB spill. R7 150us:
// GRID=1024 didn't raise occupancy (combined regs >256 cap residency) and
// doubled prep cost. R8 190us: c-outer + (256,3) -> 270MB spill (WRITE 196MB);
// but prep-offload worked (bank conflicts 0, prep cost gone).
// Conclusion: 2 waves/SIMD is the register-feasible occupancy; the limiter is
// intra-wave dependency latency (R1: ~24.5k cyc/tile wall vs ~3k issue).
// R9: R8 structure with the PROVEN (256,2) budget (no spill), GRID=512
// (one resident batch, 10 tiles/wave), + coordinate prefetch pipeline
// (next tile's x,y,z loads issued at body top, hidden under ~3k cyc of work),
// + packed per-j consts {wx,wy,wz,c1} as float4 (1 b128 + 1 b32 LDS read per
// activation instead of 5 b32).
//
// Math (unchanged): per interior point, Helmholtz residual = 5 matvecs
// through W2: rows h1,g1x,g1y,g1z,s1 -> z2,ux,uy,uz,t; h2=tanh(z2+b2);
// lap_k=d2*(t-2*h2*(ux^2+uy^2+uz^2)); helm=(lap_k+4*h2)@W3(+4*b3).
// C/D layout col=lane&15(=k), row=(lane>>4)*4+reg(=point) -> lane-local
// epilogue + 16-lane shfl reduce. fp16 absmax ~0.008 vs 0.27 threshold.

#define N_INT 262144
#define N_BC  65536
#define HID   128
#define GRID  512
#define WPB   4                      // waves per 256-thread block
#define NWAVE (GRID * WPB)           // 2048 waves
#define TILES_INT (N_INT / 16)       // 16384
#define TILES_BC  (N_BC / 16)        // 4096
#define TILES_ALL (TILES_INT + TILES_BC)   // 20480 = 2048 * 10, no tail

typedef _Float16 h8 __attribute__((ext_vector_type(8)));
typedef float    f4 __attribute__((ext_vector_type(4)));

__device__ __forceinline__ float ftanh(float x) {
    // tanh(x) = 1 - 2/(e^{2x}+1); v_exp_f32 + v_rcp_f32, ~2 ulp, inf-safe
    float e = __expf(2.0f * x);
    return 1.0f - 2.0f * __builtin_amdgcn_rcpf(e + 1.0f);
}

// ---------------- one-time prep: pack W2 + derived consts into ws ----------
// wsB (offset 0):      16384 fp16 = 32 KiB, B-frag order:
//   wsB[(((s*8+c)*64)+(qd*16+nn))*8+i] = fp16 W2[s*32+qd*8+i][c*16+nn]
// wsF (offset 32768):  1024 f32 = 4 KiB:
//   [0:512)   P[j] = float4{Wx,Wy,Wz,C1}[j], C1 = b1 + latent@W1[3:]
//   [512:640) Q2 = -2*(Wx^2+Wy^2+Wz^2)
//   [640:768) b2
//   [768:1024) W3 (128x2 interleaved)
extern "C" __global__ void pde_prep(const float* __restrict__ latent,
                                    const float* __restrict__ W1,
                                    const float* __restrict__ b1,
                                    const float* __restrict__ W2,
                                    const float* __restrict__ b2,
                                    const float* __restrict__ W3,
                                    _Float16* __restrict__ wsB,
                                    float* __restrict__ wsF)
{
    const int tid = threadIdx.x;
    for (int e = 0; e < 64; ++e) {
        int idx = e * 256 + tid;                   // coalesced over W2 row-major
        int j = idx >> 7, n = idx & 127;           // j = K row, n = out col
        int s = j >> 5, qd = (j >> 3) & 3, i = j & 7;
        int c = n >> 4,  nn = n & 15;
        wsB[(((s * 8 + c) * 64) + (qd * 16 + nn)) * 8 + i] = (_Float16)W2[idx];
    }
    // latent reduction: 2 threads per column, 32-deep chains, shfl combine
    {
        int col = tid >> 1, h = tid & 1;
        float acc = 0.0f;
        #pragma unroll
        for (int l = 0; l < 32; ++l)
            acc = fmaf(latent[32 * h + l], W1[(3 + 32 * h + l) * HID + col], acc);
        acc += __shfl_xor(acc, 1);
        if (h == 0) wsF[4 * col + 3] = acc + b1[col];   // P[col].w = C1
    }
    if (tid < HID) {
        float wx = W1[tid], wy = W1[HID + tid], wz = W1[2 * HID + tid];
        wsF[4 * tid]     = wx;                          // P[tid].x
        wsF[4 * tid + 1] = wy;                          // P[tid].y
        wsF[4 * tid + 2] = wz;                          // P[tid].z
        wsF[512 + tid] = -2.0f * fmaf(wx, wx, fmaf(wy, wy, wz * wz));
        wsF[640 + tid] = b2[tid];
        wsF[768 + 2 * tid]     = W3[2 * tid];
        wsF[768 + 2 * tid + 1] = W3[2 * tid + 1];
    }
}

extern "C" __global__ __launch_bounds__(256, 2)
void pde_mfma(const float* __restrict__ ci, const float* __restrict__ cb,
              const float* __restrict__ gt, const float* __restrict__ b3,
              const _Float16* __restrict__ wsB, const float* __restrict__ wsF,
              float* __restrict__ out)
{
    __shared__ float4 sBv[2048];       // 32 KiB packed W2 B-frags
    __shared__ float4 sFv[256];        // 4 KiB derived consts
    _Float16* sB = (_Float16*)sBv;
    const float*  sF  = (const float*)sFv;
    const float4* sP  = (const float4*)sF;          // {wx,wy,wz,c1}[j]
    const float*  sQ2 = sF + 512;
    const float*  sB2 = sF + 640;
    const float2* sW3 = (const float2*)(sF + 768);

    const int tid = threadIdx.x;

    // conflict-free staging copy: 32 KiB + 4 KiB as float4
    #pragma unroll
    for (int e = 0; e < 8; ++e)
        sBv[e * 256 + tid] = ((const float4*)wsB)[e * 256 + tid];
    sFv[tid] = ((const float4*)wsF)[tid];
    __syncthreads();

    const int lane = tid & 63;
    const int m    = lane & 15;        // point-in-tile
    const int qd   = lane >> 4;        // quad: k-subrange / C row block
    const int wgid = blockIdx.x * WPB + (tid >> 6);
    const float b30 = b3[0], b31 = b3[1];
    const f4 z4 = {0.0f, 0.0f, 0.0f, 0.0f};

    float lsum = 0.0f, bsum = 0.0f;

    // coordinate pipeline: coords for tile t preloaded before body
    int t = wgid;
    const float* cp0 = (t < TILES_INT) ? (ci + 3 * (t * 16 + m))
                                       : (cb + 3 * ((t - TILES_INT) * 16 + m));
    float x = cp0[0], y = cp0[1], z = cp0[2];

    for (; t < TILES_ALL; t += NWAVE) {
      // issue next tile's coord loads now; consumed next iteration
      float nx, ny, nz;
      {
        int tn = t + NWAVE;
        if (tn < TILES_ALL) {
            const float* np = (tn < TILES_INT) ? (ci + 3 * (tn * 16 + m))
                                               : (cb + 3 * ((tn - TILES_INT) * 16 + m));
            nx = np[0]; ny = np[1]; nz = np[2];
        } else { nx = ny = nz = 0.0f; }
      }

      if (t < TILES_INT) {
        // ================= interior tile: 16 points =================
        const int p0 = t * 16;

        // A-frags for all 4 k-slices (80 VGPRs live)
        h8 FH[4], FX[4], FY[4], FZ[4], FT[4];
        #pragma unroll
        for (int s = 0; s < 4; ++s) {
            const int j0 = s * 32 + qd * 8;
            #pragma unroll
            for (int i = 0; i < 8; ++i) {
                const int j = j0 + i;
                float4 P = sP[j];                  // {wx,wy,wz,c1}
                float z1 = fmaf(x, P.x, fmaf(y, P.y, fmaf(z, P.z, P.w)));
                float h  = ftanh(z1);
                float d  = fmaf(-h, h, 1.0f);
                FH[s][i] = (_Float16)h;
                FX[s][i] = (_Float16)(d * P.x);
                FY[s][i] = (_Float16)(d * P.y);
                FZ[s][i] = (_Float16)(d * P.z);
                FT[s][i] = (_Float16)(sQ2[j] * h * d);
            }
        }

        float yr[4] = {0,0,0,0}, yi[4] = {0,0,0,0};
        float lr[4] = {0,0,0,0}, li[4] = {0,0,0,0};
        #pragma unroll
        for (int c = 0; c < 8; ++c) {
            f4 aZ = z4, aX = z4, aY = z4, aW = z4, aT = z4;
            #pragma unroll
            for (int s = 0; s < 4; ++s) {
                h8 bf = *(const h8*)&sB[(((s * 8 + c) * 64) + lane) * 8];
                aZ = __builtin_amdgcn_mfma_f32_16x16x32_f16(FH[s], bf, aZ, 0, 0, 0);
                aX = __builtin_amdgcn_mfma_f32_16x16x32_f16(FX[s], bf, aX, 0, 0, 0);
                aY = __builtin_amdgcn_mfma_f32_16x16x32_f16(FY[s], bf, aY, 0, 0, 0);
                aW = __builtin_amdgcn_mfma_f32_16x16x32_f16(FZ[s], bf, aW, 0, 0, 0);
                aT = __builtin_amdgcn_mfma_f32_16x16x32_f16(FT[s], bf, aT, 0, 0, 0);
            }
            // fused epilogue for this c: lane-local (point=qd*4+r, k=c*16+m)
            const int k = c * 16 + m;
            const float b2k = sB2[k];
            const float2 w3 = sW3[k];
            #pragma unroll
            for (int r = 0; r < 4; ++r) {
                float h2 = ftanh(aZ[r] + b2k);
                float d2 = fmaf(-h2, h2, 1.0f);
                float uu = fmaf(aX[r], aX[r], fmaf(aY[r], aY[r], aW[r] * aW[r]));
                float lk = d2 * fmaf(-2.0f * h2, uu, aT[r]);
                yr[r] = fmaf(h2, w3.x, yr[r]);
                yi[r] = fmaf(h2, w3.y, yi[r]);
                lr[r] = fmaf(lk, w3.x, lr[r]);
                li[r] = fmaf(lk, w3.y, li[r]);
            }
        }
        #pragma unroll
        for (int off = 1; off <= 8; off <<= 1) {
            #pragma unroll
            for (int r = 0; r < 4; ++r) {
                yr[r] += __shfl_xor(yr[r], off);
                yi[r] += __shfl_xor(yi[r], off);
                lr[r] += __shfl_xor(lr[r], off);
                li[r] += __shfl_xor(li[r], off);
            }
        }
        if (m == 0) {
            #pragma unroll
            for (int r = 0; r < 4; ++r) {
                float re = fmaf(4.0f, yr[r] + b30, lr[r]);
                float im = fmaf(4.0f, yi[r] + b31, li[r]);
                out[2 + p0 + qd * 4 + r] = re;
                lsum = fmaf(re, re, fmaf(im, im, lsum));
            }
        }
      } else {
        // ================= boundary tile: 16 points, forward only =================
        const int q0 = (t - TILES_INT) * 16;

        h8 FH[4];
        #pragma unroll
        for (int s = 0; s < 4; ++s) {
            const int j0 = s * 32 + qd * 8;
            #pragma unroll
            for (int i = 0; i < 8; ++i) {
                const int j = j0 + i;
                float4 P = sP[j];
                float z1 = fmaf(x, P.x, fmaf(y, P.y, fmaf(z, P.z, P.w)));
                FH[s][i] = (_Float16)ftanh(z1);
            }
        }

        float yr[4] = {0,0,0,0}, yi[4] = {0,0,0,0};
        #pragma unroll
        for (int c = 0; c < 8; ++c) {
            f4 aZ = z4;
            #pragma unroll
            for (int s = 0; s < 4; ++s) {
                h8 bf = *(const h8*)&sB[(((s * 8 + c) * 64) + lane) * 8];
                aZ = __builtin_amdgcn_mfma_f32_16x16x32_f16(FH[s], bf, aZ, 0, 0, 0);
            }
            const int k = c * 16 + m;
            const float b2k = sB2[k];
            const float2 w3 = sW3[k];
            #pragma unroll
            for (int r = 0; r < 4; ++r) {
                float h2 = ftanh(aZ[r] + b2k);
                yr[r] = fmaf(h2, w3.x, yr[r]);
                yi[r] = fmaf(h2, w3.y, yi[r]);
            }
        }
        #pragma unroll
        for (int off = 1; off <= 8; off <<= 1) {
            #pragma unroll
            for (int r = 0; r < 4; ++r) {
                yr[r] += __shfl_xor(yr[r], off);
                yi[r] += __shfl_xor(yi[r], off);
            }
        }
        if (m == 0) {
            #pragma unroll
            for (int r = 0; r < 4; ++r) {
                float dr = yr[r] + b30 - gt[q0 + qd * 4 + r];
                float di = yi[r] + b31;
                bsum = fmaf(dr, dr, fmaf(di, di, bsum));
            }
        }
      }

      x = nx; y = ny; z = nz;
    }

    // wave-wide loss reduction, one atomic per wave
    #pragma unroll
    for (int off = 1; off < 64; off <<= 1) {
        lsum += __shfl_xor(lsum, off);
        bsum += __shfl_xor(bsum, off);
    }
    if (lane == 0) {
        atomicAdd(out,     lsum * (1.0f / (float)N_INT));
        atomicAdd(out + 1, bsum * (1.0f / (float)N_BC));
    }
}

extern "C" void kernel_launch(void* const* d_in, const int* in_sizes, int n_in,
                              void* d_out, int out_size, void* d_ws, size_t ws_size,
                              hipStream_t stream)
{
    const float* ci  = (const float*)d_in[0];   // coords_int (262144,3)
    const float* cb  = (const float*)d_in[1];   // coords_bc  (65536,3)
    const float* gt  = (const float*)d_in[2];   // gt_bc      (65536,1)
    const float* lat = (const float*)d_in[3];   // latent     (64,)
    const float* W1  = (const float*)d_in[4];   // (67,128)
    const float* b1  = (const float*)d_in[5];   // (128,)
    const float* W2  = (const float*)d_in[6];   // (128,128)
    const float* b2  = (const float*)d_in[7];   // (128,)
    const float* W3  = (const float*)d_in[8];   // (128,2)
    const float* b3  = (const float*)d_in[9];   // (2,)
    float* out = (float*)d_out;   // [loss_pde, loss_bc, re(helm)*N_INT]

    _Float16* wsB = (_Float16*)d_ws;                       // 32 KiB packed W2
    float*    wsF = (float*)((char*)d_ws + 32768);         // 4 KiB consts

    // zero the two loss accumulators (out is poisoned 0xAA before every call)
    hipMemsetAsync(d_out, 0, 2 * sizeof(float), stream);

    hipLaunchKernelGGL(pde_prep, dim3(1), dim3(256), 0, stream,
                       lat, W1, b1, W2, b2, W3, wsB, wsF);
    hipLaunchKernelGGL(pde_mfma, dim3(GRID), dim3(256), 0, stream,
                       ci, cb, gt, b3, wsB, wsF, out);
}